// Round 1
// baseline (161.695 us; speedup 1.0000x reference)
//
#include <hip/hip_runtime.h>
#include <math.h>

// ---------------------------------------------------------------------------
// Kernel 0: build the 8x8 complex unitary U of the 2-layer VQC from the 12
// angles. Lane j (j<8) evolves basis state e_j through the circuit; column j
// of U is the result. Stored to ws: ws[0..63]=Re(U)[i*8+j], ws[64..127]=Im(U).
// Wire 0 = MSB: qubit q <-> bit (4 >> q) of the flat index.
// ---------------------------------------------------------------------------
__global__ __launch_bounds__(64) void vqc_build_u(const float* __restrict__ wq,
                                                  float* __restrict__ Uws) {
  const int j = threadIdx.x;
  if (j >= 8) return;
  float ar[8], ai[8];
#pragma unroll
  for (int i = 0; i < 8; ++i) { ar[i] = (i == j) ? 1.f : 0.f; ai[i] = 0.f; }

#pragma unroll
  for (int l = 0; l < 2; ++l) {
    // RY(theta) on q = 0,1,2 : [[c,-s],[s,c]], c=cos(theta/2)
#pragma unroll
    for (int q = 0; q < 3; ++q) {
      const float th = 0.5f * wq[l * 6 + q];
      const float c = cosf(th), s = sinf(th);
      const int bit = 4 >> q;
#pragma unroll
      for (int i0 = 0; i0 < 8; ++i0) {
        if (i0 & bit) continue;
        const int i1 = i0 | bit;
        const float r0 = ar[i0], m0 = ai[i0], r1 = ar[i1], m1 = ai[i1];
        ar[i0] = c * r0 - s * r1;  ai[i0] = c * m0 - s * m1;
        ar[i1] = s * r0 + c * r1;  ai[i1] = s * m0 + c * m1;
      }
    }
    // RZ(theta): diag(e^{-i th/2}, e^{+i th/2})
#pragma unroll
    for (int q = 0; q < 3; ++q) {
      const float th = 0.5f * wq[l * 6 + 3 + q];
      const float c = cosf(th), s = sinf(th);
      const int bit = 4 >> q;
#pragma unroll
      for (int i = 0; i < 8; ++i) {
        const float r = ar[i], m = ai[i];
        if (i & bit) { ar[i] = r * c - m * s;  ai[i] = m * c + r * s; }
        else         { ar[i] = r * c + m * s;  ai[i] = m * c - r * s; }
      }
    }
    // CNOT (0,1),(1,2),(2,0) -> (cbit,tbit) = (4,2),(2,1),(1,4)
#pragma unroll
    for (int k = 0; k < 3; ++k) {
      const int cb = (k == 0) ? 4 : (k == 1) ? 2 : 1;
      const int tb = (k == 0) ? 2 : (k == 1) ? 1 : 4;
#pragma unroll
      for (int i = 0; i < 8; ++i) {
        if ((i & cb) && !(i & tb)) {
          const int i1 = i | tb;
          float t;
          t = ar[i]; ar[i] = ar[i1]; ar[i1] = t;
          t = ai[i]; ai[i] = ai[i1]; ai[i1] = t;
        }
      }
    }
  }
#pragma unroll
  for (int i = 0; i < 8; ++i) {
    Uws[i * 8 + j]      = ar[i];
    Uws[64 + i * 8 + j] = ai[i];
  }
}

// ---------------------------------------------------------------------------
// Kernel 1: GEMV  out[r*11 + v] = dot(x[r,:], W[v,:])  (raw, no bias/tanh).
// One row per wave. Lane l covers columns {l*4..l*4+3} and {256+l*4..+3};
// W (8x512) lives in 64 VGPRs per lane. Two coalesced dwordx4 loads per lane
// per row, 64 FMAs, 6-step xor-butterfly over 8 partial sums.
// ---------------------------------------------------------------------------
__global__ __launch_bounds__(256) void vqc_gemv8(const float* __restrict__ x,
                                                 const float* __restrict__ W,
                                                 float* __restrict__ out, int B) {
  const int lane = threadIdx.x & 63;
  const int wid  = blockIdx.x * (blockDim.x >> 6) + (threadIdx.x >> 6);
  const int nw   = gridDim.x * (blockDim.x >> 6);

  float w0[8][4], w1[8][4];
#pragma unroll
  for (int v = 0; v < 8; ++v) {
    const float4 a = *(const float4*)(W + v * 512 + lane * 4);
    const float4 b = *(const float4*)(W + v * 512 + 256 + lane * 4);
    w0[v][0] = a.x; w0[v][1] = a.y; w0[v][2] = a.z; w0[v][3] = a.w;
    w1[v][0] = b.x; w1[v][1] = b.y; w1[v][2] = b.z; w1[v][3] = b.w;
  }

  for (int r = wid; r < B; r += nw) {
    const float4* xr = (const float4*)(x + (size_t)r * 512);
    const float4 xa = xr[lane];        // bytes [lane*16)        -> cols lane*4+{0..3}
    const float4 xb = xr[64 + lane];   // bytes [1024 + lane*16) -> cols 256+lane*4+{0..3}
    float acc[8];
#pragma unroll
    for (int v = 0; v < 8; ++v) {
      float s = xa.x * w0[v][0];
      s = fmaf(xa.y, w0[v][1], s);
      s = fmaf(xa.z, w0[v][2], s);
      s = fmaf(xa.w, w0[v][3], s);
      s = fmaf(xb.x, w1[v][0], s);
      s = fmaf(xb.y, w1[v][1], s);
      s = fmaf(xb.z, w1[v][2], s);
      s = fmaf(xb.w, w1[v][3], s);
      acc[v] = s;
    }
#pragma unroll
    for (int m = 1; m < 64; m <<= 1) {
#pragma unroll
      for (int v = 0; v < 8; ++v) acc[v] += __shfl_xor(acc[v], m, 64);
    }
    if (lane == 0) {
      float* o = out + (size_t)r * 11;
#pragma unroll
      for (int v = 0; v < 8; ++v) o[v] = acc[v];
    }
  }
}

// ---------------------------------------------------------------------------
// Kernel 2: per-row epilogue. Reads the 8 raw dots from out[r*11..], applies
// bias+tanh, L2-normalize (eps=1e-12), applies U (8x8 complex x real vec),
// computes probs and <Z_q>, writes all 11 outputs.
// ---------------------------------------------------------------------------
__global__ __launch_bounds__(256) void vqc_epilogue(float* __restrict__ out,
                                                    const float* __restrict__ bias,
                                                    const float* __restrict__ Uws,
                                                    int B) {
  __shared__ float sU[128];
  __shared__ float sb[8];
  if (threadIdx.x < 128) sU[threadIdx.x] = Uws[threadIdx.x];
  if (threadIdx.x < 8)   sb[threadIdx.x] = bias[threadIdx.x];
  __syncthreads();

  const int r = blockIdx.x * blockDim.x + threadIdx.x;
  if (r >= B) return;
  float* o = out + (size_t)r * 11;

  float p[8];
  float ss = 0.f;
#pragma unroll
  for (int j = 0; j < 8; ++j) {
    const float v = tanhf(o[j] + sb[j]);
    p[j] = v;
    ss = fmaf(v, v, ss);
  }
  const float inv = 1.0f / fmaxf(sqrtf(ss), 1e-12f);
  float a[8];
#pragma unroll
  for (int j = 0; j < 8; ++j) a[j] = p[j] * inv;

  float pr[8];
#pragma unroll
  for (int i = 0; i < 8; ++i) {
    float cr = 0.f, ci = 0.f;
#pragma unroll
    for (int jj = 0; jj < 8; ++jj) {
      cr = fmaf(sU[i * 8 + jj],      a[jj], cr);
      ci = fmaf(sU[64 + i * 8 + jj], a[jj], ci);
    }
    pr[i] = cr * cr + ci * ci;
  }
  // qubit0 bit=4, qubit1 bit=2, qubit2 bit=1; <Z> = sum(bit clear) - sum(bit set)
  const float z0 = (pr[0] + pr[1] + pr[2] + pr[3]) - (pr[4] + pr[5] + pr[6] + pr[7]);
  const float z1 = (pr[0] + pr[1] + pr[4] + pr[5]) - (pr[2] + pr[3] + pr[6] + pr[7]);
  const float z2 = (pr[0] + pr[2] + pr[4] + pr[6]) - (pr[1] + pr[3] + pr[5] + pr[7]);

#pragma unroll
  for (int j = 0; j < 8; ++j) o[j] = p[j];
  o[8] = z0; o[9] = z1; o[10] = z2;
}

extern "C" void kernel_launch(void* const* d_in, const int* in_sizes, int n_in,
                              void* d_out, int out_size, void* d_ws, size_t ws_size,
                              hipStream_t stream) {
  const float* x  = (const float*)d_in[0];   // (B, 512)
  const float* W  = (const float*)d_in[1];   // (8, 512)
  const float* b  = (const float*)d_in[2];   // (8,)
  const float* wq = (const float*)d_in[3];   // (2, 2, 3)
  float* out = (float*)d_out;                // (B, 11)
  float* Uws = (float*)d_ws;                 // 128 floats

  const int B = in_sizes[0] / 512;

  vqc_build_u<<<1, 64, 0, stream>>>(wq, Uws);
  vqc_gemv8<<<2048, 256, 0, stream>>>(x, W, out, B);
  vqc_epilogue<<<(B + 255) / 256, 256, 0, stream>>>(out, b, Uws, B);
}

// Round 2
// 114.952 us; speedup vs baseline: 1.4066x; 1.4066x over previous
//
#include <hip/hip_runtime.h>
#include <math.h>

// ---------------------------------------------------------------------------
// Kernel 0: build the 8x8 complex unitary U of the 2-layer VQC from the 12
// angles. Lane j (j<8) evolves basis state e_j through the circuit; column j
// of U is the result. Stored to ws: ws[0..63]=Re(U)[i*8+j], ws[64..127]=Im(U).
// Wire 0 = MSB: qubit q <-> bit (4 >> q) of the flat index.
// ---------------------------------------------------------------------------
__global__ __launch_bounds__(64) void vqc_build_u(const float* __restrict__ wq,
                                                  float* __restrict__ Uws) {
  const int j = threadIdx.x;
  if (j >= 8) return;
  float ar[8], ai[8];
#pragma unroll
  for (int i = 0; i < 8; ++i) { ar[i] = (i == j) ? 1.f : 0.f; ai[i] = 0.f; }

#pragma unroll
  for (int l = 0; l < 2; ++l) {
    // RY(theta) on q = 0,1,2 : [[c,-s],[s,c]], c=cos(theta/2)
#pragma unroll
    for (int q = 0; q < 3; ++q) {
      const float th = 0.5f * wq[l * 6 + q];
      const float c = cosf(th), s = sinf(th);
      const int bit = 4 >> q;
#pragma unroll
      for (int i0 = 0; i0 < 8; ++i0) {
        if (i0 & bit) continue;
        const int i1 = i0 | bit;
        const float r0 = ar[i0], m0 = ai[i0], r1 = ar[i1], m1 = ai[i1];
        ar[i0] = c * r0 - s * r1;  ai[i0] = c * m0 - s * m1;
        ar[i1] = s * r0 + c * r1;  ai[i1] = s * m0 + c * m1;
      }
    }
    // RZ(theta): diag(e^{-i th/2}, e^{+i th/2})
#pragma unroll
    for (int q = 0; q < 3; ++q) {
      const float th = 0.5f * wq[l * 6 + 3 + q];
      const float c = cosf(th), s = sinf(th);
      const int bit = 4 >> q;
#pragma unroll
      for (int i = 0; i < 8; ++i) {
        const float r = ar[i], m = ai[i];
        if (i & bit) { ar[i] = r * c - m * s;  ai[i] = m * c + r * s; }
        else         { ar[i] = r * c + m * s;  ai[i] = m * c - r * s; }
      }
    }
    // CNOT (0,1),(1,2),(2,0) -> (cbit,tbit) = (4,2),(2,1),(1,4)
#pragma unroll
    for (int k = 0; k < 3; ++k) {
      const int cb = (k == 0) ? 4 : (k == 1) ? 2 : 1;
      const int tb = (k == 0) ? 2 : (k == 1) ? 1 : 4;
#pragma unroll
      for (int i = 0; i < 8; ++i) {
        if ((i & cb) && !(i & tb)) {
          const int i1 = i | tb;
          float t;
          t = ar[i]; ar[i] = ar[i1]; ar[i1] = t;
          t = ai[i]; ai[i] = ai[i1]; ai[i1] = t;
        }
      }
    }
  }
#pragma unroll
  for (int i = 0; i < 8; ++i) {
    Uws[i * 8 + j]      = ar[i];
    Uws[64 + i * 8 + j] = ai[i];
  }
}

// ---------------------------------------------------------------------------
// Fused kernel: GEMV + tanh + normalize + U matvec + probs + <Z>, one pass.
// One row per wave iteration for the GEMV (64 lanes x 8 cols each, weights
// in 64 VGPRs). Reduction uses the HALVING butterfly: masks 1,2,4 shrink the
// 8-vector 8->4->2->1 (7 shuffles), masks 8,16,32 finish (3 shuffles); lane
// ends holding the dot for v = bitrev3(lane&7) == myv.
// 8 rows are batched: row t's dot is kept by 8-lane group t (1 cndmask/row);
// the epilogue then runs fully lane-parallel (group = row, lane-in-group = v)
// with all cross-lane reductions confined to masks 1,2,4 (group-local).
// ---------------------------------------------------------------------------
__global__ __launch_bounds__(256, 4) void vqc_fused(const float* __restrict__ x,
                                                    const float* __restrict__ W,
                                                    const float* __restrict__ bias,
                                                    const float* __restrict__ Uws,
                                                    float* __restrict__ out, int B) {
  const int lane = threadIdx.x & 63;
  const int wid  = blockIdx.x * (blockDim.x >> 6) + (threadIdx.x >> 6);
  const int nw   = gridDim.x * (blockDim.x >> 6);
  const bool b0 = (lane & 1) != 0;
  const bool b1 = (lane & 2) != 0;
  const bool b2 = (lane & 4) != 0;
  const int grp = lane >> 3;
  const int myv = ((lane & 1) << 2) | (lane & 2) | ((lane >> 2) & 1);  // bitrev3(lane&7)

  // W (8x512) resident in 64 VGPRs/lane; lane covers cols lane*4..+3, 256+lane*4..+3
  float w0[8][4], w1[8][4];
#pragma unroll
  for (int v = 0; v < 8; ++v) {
    const float4 a = *(const float4*)(W + v * 512 + lane * 4);
    const float4 b = *(const float4*)(W + v * 512 + 256 + lane * 4);
    w0[v][0] = a.x; w0[v][1] = a.y; w0[v][2] = a.z; w0[v][3] = a.w;
    w1[v][0] = b.x; w1[v][1] = b.y; w1[v][2] = b.z; w1[v][3] = b.w;
  }
  // U column myv + bias[myv], loop-invariant per lane
  float Ur[8], Ui[8];
#pragma unroll
  for (int i = 0; i < 8; ++i) {
    Ur[i] = Uws[i * 8 + myv];
    Ui[i] = Uws[64 + i * 8 + myv];
  }
  const float bv = bias[myv];

  const int nbatch = (B + 7) >> 3;
  for (int rb = wid; rb < nbatch; rb += nw) {
    const int r0 = rb << 3;
    float myd = 0.f;  // this lane's dot: row r0+grp, vector myv
#pragma unroll
    for (int t = 0; t < 8; ++t) {
      const int r = r0 + t;
      if (r < B) {
        const float4* xr = (const float4*)(x + (size_t)r * 512);
        const float4 xa = xr[lane];
        const float4 xb = xr[64 + lane];
        float acc[8];
#pragma unroll
        for (int v = 0; v < 8; ++v) {
          float s = xa.x * w0[v][0];
          s = fmaf(xa.y, w0[v][1], s);
          s = fmaf(xa.z, w0[v][2], s);
          s = fmaf(xa.w, w0[v][3], s);
          s = fmaf(xb.x, w1[v][0], s);
          s = fmaf(xb.y, w1[v][1], s);
          s = fmaf(xb.z, w1[v][2], s);
          s = fmaf(xb.w, w1[v][3], s);
          acc[v] = s;
        }
        // halving reduce: 8 vals over 64 lanes -> 1 val/lane (v = myv)
        float s4[4];
#pragma unroll
        for (int i = 0; i < 4; ++i) {
          const float keep = b0 ? acc[i + 4] : acc[i];
          const float send = b0 ? acc[i] : acc[i + 4];
          s4[i] = keep + __shfl_xor(send, 1, 64);
        }
        float s2[2];
#pragma unroll
        for (int i = 0; i < 2; ++i) {
          const float keep = b1 ? s4[i + 2] : s4[i];
          const float send = b1 ? s4[i] : s4[i + 2];
          s2[i] = keep + __shfl_xor(send, 2, 64);
        }
        const float keep = b2 ? s2[1] : s2[0];
        const float send = b2 ? s2[0] : s2[1];
        float s1 = keep + __shfl_xor(send, 4, 64);
        s1 += __shfl_xor(s1, 8, 64);
        s1 += __shfl_xor(s1, 16, 64);
        s1 += __shfl_xor(s1, 32, 64);
        myd = (grp == t) ? s1 : myd;
      }
    }

    // ---- epilogue: 8 rows in parallel (group = row, lane-in-group = myv) ----
    const int row = r0 + grp;
    const float p = tanhf(myd + bv);
    float ss = p * p;
    ss += __shfl_xor(ss, 1, 64);
    ss += __shfl_xor(ss, 2, 64);
    ss += __shfl_xor(ss, 4, 64);
    const float av = p * (1.0f / fmaxf(sqrtf(ss), 1e-12f));

    // complex matvec: lane contributes column myv; halving-reduce the
    // 16-vector [cr0,ci0,cr1,ci1,...] over the 8-lane group
    float q[16];
#pragma unroll
    for (int i = 0; i < 8; ++i) {
      q[2 * i]     = Ur[i] * av;
      q[2 * i + 1] = Ui[i] * av;
    }
    float n8[8];
#pragma unroll
    for (int i = 0; i < 8; ++i) {
      const float k1 = b0 ? q[i + 8] : q[i];
      const float s1v = b0 ? q[i] : q[i + 8];
      n8[i] = k1 + __shfl_xor(s1v, 1, 64);
    }
    float n4[4];
#pragma unroll
    for (int i = 0; i < 4; ++i) {
      const float k2 = b1 ? n8[i + 4] : n8[i];
      const float s2v = b1 ? n8[i] : n8[i + 4];
      n4[i] = k2 + __shfl_xor(s2v, 2, 64);
    }
    float n2[2];
#pragma unroll
    for (int i = 0; i < 2; ++i) {
      const float k3 = b2 ? n4[i + 2] : n4[i];
      const float s3v = b2 ? n4[i] : n4[i + 2];
      n2[i] = k3 + __shfl_xor(s3v, 4, 64);
    }
    // lane holds cr,ci for state index i = myv
    const float pr = n2[0] * n2[0] + n2[1] * n2[1];
    // <Z_q>: sign by bit (4>>q) of state index
    float t0 = (myv & 4) ? -pr : pr;
    float t1 = (myv & 2) ? -pr : pr;
    float t2 = (myv & 1) ? -pr : pr;
#pragma unroll
    for (int m = 1; m <= 4; m <<= 1) {
      t0 += __shfl_xor(t0, m, 64);
      t1 += __shfl_xor(t1, m, 64);
      t2 += __shfl_xor(t2, m, 64);
    }
    if (row < B) {
      float* o = out + (size_t)row * 11;
      o[myv] = p;
      if (myv < 3) o[8 + myv] = (myv == 0) ? t0 : ((myv == 1) ? t1 : t2);
    }
  }
}

extern "C" void kernel_launch(void* const* d_in, const int* in_sizes, int n_in,
                              void* d_out, int out_size, void* d_ws, size_t ws_size,
                              hipStream_t stream) {
  const float* x  = (const float*)d_in[0];   // (B, 512)
  const float* W  = (const float*)d_in[1];   // (8, 512)
  const float* b  = (const float*)d_in[2];   // (8,)
  const float* wq = (const float*)d_in[3];   // (2, 2, 3)
  float* out = (float*)d_out;                // (B, 11)
  float* Uws = (float*)d_ws;                 // 128 floats

  const int B = in_sizes[0] / 512;

  vqc_build_u<<<1, 64, 0, stream>>>(wq, Uws);
  vqc_fused<<<2048, 256, 0, stream>>>(x, W, b, Uws, out, B);
}

// Round 4
// 114.858 us; speedup vs baseline: 1.4078x; 1.0008x over previous
//
#include <hip/hip_runtime.h>
#include <math.h>

// ---------------------------------------------------------------------------
// Kernel 0: build the 8x8 complex unitary U of the 2-layer VQC from the 12
// angles. Lane j (j<8) evolves basis state e_j through the circuit; column j
// of U is the result. Stored to ws: ws[0..63]=Re(U)[i*8+j], ws[64..127]=Im(U).
// Wire 0 = MSB: qubit q <-> bit (4 >> q) of the flat index.
// ---------------------------------------------------------------------------
__global__ __launch_bounds__(64) void vqc_build_u(const float* __restrict__ wq,
                                                  float* __restrict__ Uws) {
  const int j = threadIdx.x;
  if (j >= 8) return;
  float ar[8], ai[8];
#pragma unroll
  for (int i = 0; i < 8; ++i) { ar[i] = (i == j) ? 1.f : 0.f; ai[i] = 0.f; }

#pragma unroll
  for (int l = 0; l < 2; ++l) {
    // RY(theta) on q = 0,1,2 : [[c,-s],[s,c]], c=cos(theta/2)
#pragma unroll
    for (int q = 0; q < 3; ++q) {
      const float th = 0.5f * wq[l * 6 + q];
      const float c = cosf(th), s = sinf(th);
      const int bit = 4 >> q;
#pragma unroll
      for (int i0 = 0; i0 < 8; ++i0) {
        if (i0 & bit) continue;
        const int i1 = i0 | bit;
        const float r0 = ar[i0], m0 = ai[i0], r1 = ar[i1], m1 = ai[i1];
        ar[i0] = c * r0 - s * r1;  ai[i0] = c * m0 - s * m1;
        ar[i1] = s * r0 + c * r1;  ai[i1] = s * m0 + c * m1;
      }
    }
    // RZ(theta): diag(e^{-i th/2}, e^{+i th/2})
#pragma unroll
    for (int q = 0; q < 3; ++q) {
      const float th = 0.5f * wq[l * 6 + 3 + q];
      const float c = cosf(th), s = sinf(th);
      const int bit = 4 >> q;
#pragma unroll
      for (int i = 0; i < 8; ++i) {
        const float r = ar[i], m = ai[i];
        if (i & bit) { ar[i] = r * c - m * s;  ai[i] = m * c + r * s; }
        else         { ar[i] = r * c + m * s;  ai[i] = m * c - r * s; }
      }
    }
    // CNOT (0,1),(1,2),(2,0) -> (cbit,tbit) = (4,2),(2,1),(1,4)
#pragma unroll
    for (int k = 0; k < 3; ++k) {
      const int cb = (k == 0) ? 4 : (k == 1) ? 2 : 1;
      const int tb = (k == 0) ? 2 : (k == 1) ? 1 : 4;
#pragma unroll
      for (int i = 0; i < 8; ++i) {
        if ((i & cb) && !(i & tb)) {
          const int i1 = i | tb;
          float t;
          t = ar[i]; ar[i] = ar[i1]; ar[i1] = t;
          t = ai[i]; ai[i] = ai[i1]; ai[i1] = t;
        }
      }
    }
  }
#pragma unroll
  for (int i = 0; i < 8; ++i) {
    Uws[i * 8 + j]      = ar[i];
    Uws[64 + i * 8 + j] = ai[i];
  }
}

// ---------------------------------------------------------------------------
// Fused kernel: GEMV + tanh + normalize + U matvec + probs + <Z>, one pass.
// Identical cross-lane structure to the verified R1 kernel (__shfl_xor only;
// halving butterfly, myv = bitrev3(lane&7), grp = lane>>3). ONE change:
// the whole 8-row batch (16 x dwordx4 = 16 KB/wave) is preloaded into
// registers up-front, so ~16 loads are outstanding instead of 2 -> the
// HBM latency (~900 cyc) is covered and the kernel becomes BW-bound.
// __launch_bounds__(256,2): ~175 VGPR fits 2 waves/SIMD without spill.
// ---------------------------------------------------------------------------
template<bool GUARD>
__global__ __launch_bounds__(256, 2) void vqc_fused(const float* __restrict__ x,
                                                    const float* __restrict__ W,
                                                    const float* __restrict__ bias,
                                                    const float* __restrict__ Uws,
                                                    float* __restrict__ out, int B) {
  const int lane = threadIdx.x & 63;
  const int wid  = blockIdx.x * (blockDim.x >> 6) + (threadIdx.x >> 6);
  const int nw   = gridDim.x * (blockDim.x >> 6);
  const bool b0 = (lane & 1) != 0;
  const bool b1 = (lane & 2) != 0;
  const bool b2 = (lane & 4) != 0;
  const int grp = lane >> 3;
  const int myv = ((lane & 1) << 2) | (lane & 2) | ((lane >> 2) & 1);  // bitrev3(lane&7)

  // W (8x512) resident in 64 VGPRs/lane; lane covers cols lane*4..+3, 256+lane*4..+3
  float w0[8][4], w1[8][4];
#pragma unroll
  for (int v = 0; v < 8; ++v) {
    const float4 a = *(const float4*)(W + v * 512 + lane * 4);
    const float4 b = *(const float4*)(W + v * 512 + 256 + lane * 4);
    w0[v][0] = a.x; w0[v][1] = a.y; w0[v][2] = a.z; w0[v][3] = a.w;
    w1[v][0] = b.x; w1[v][1] = b.y; w1[v][2] = b.z; w1[v][3] = b.w;
  }
  // U column myv + bias[myv], loop-invariant per lane
  float Ur[8], Ui[8];
#pragma unroll
  for (int i = 0; i < 8; ++i) {
    Ur[i] = Uws[i * 8 + myv];
    Ui[i] = Uws[64 + i * 8 + myv];
  }
  const float bv = bias[myv];

  const int nbatch = (B + 7) >> 3;
  for (int rb = wid; rb < nbatch; rb += nw) {
    const size_t r0 = (size_t)rb << 3;

    // ---- preload the whole 8-row batch: 16 KB/wave in flight ----
    float4 xa[8], xb[8];
#pragma unroll
    for (int t = 0; t < 8; ++t) {
      size_t r = r0 + t;
      if (GUARD) r = (r < (size_t)B) ? r : (size_t)(B - 1);
      const float4* xr = (const float4*)(x + r * 512);
      xa[t] = xr[lane];
      xb[t] = xr[64 + lane];
    }

    float myd = 0.f;  // this lane's dot: row r0+grp, vector myv
#pragma unroll
    for (int t = 0; t < 8; ++t) {
      float acc[8];
#pragma unroll
      for (int v = 0; v < 8; ++v) {
        float s = xa[t].x * w0[v][0];
        s = fmaf(xa[t].y, w0[v][1], s);
        s = fmaf(xa[t].z, w0[v][2], s);
        s = fmaf(xa[t].w, w0[v][3], s);
        s = fmaf(xb[t].x, w1[v][0], s);
        s = fmaf(xb[t].y, w1[v][1], s);
        s = fmaf(xb[t].z, w1[v][2], s);
        s = fmaf(xb[t].w, w1[v][3], s);
        acc[v] = s;
      }
      // halving reduce: 8 vals over 64 lanes -> 1 val/lane (v = myv)
      float s4[4];
#pragma unroll
      for (int i = 0; i < 4; ++i) {
        const float keep = b0 ? acc[i + 4] : acc[i];
        const float send = b0 ? acc[i] : acc[i + 4];
        s4[i] = keep + __shfl_xor(send, 1, 64);
      }
      float s2[2];
#pragma unroll
      for (int i = 0; i < 2; ++i) {
        const float keep = b1 ? s4[i + 2] : s4[i];
        const float send = b1 ? s4[i] : s4[i + 2];
        s2[i] = keep + __shfl_xor(send, 2, 64);
      }
      const float keep = b2 ? s2[1] : s2[0];
      const float send = b2 ? s2[0] : s2[1];
      float s1 = keep + __shfl_xor(send, 4, 64);
      s1 += __shfl_xor(s1, 8, 64);
      s1 += __shfl_xor(s1, 16, 64);
      s1 += __shfl_xor(s1, 32, 64);
      myd = (grp == t) ? s1 : myd;
    }

    // ---- epilogue: 8 rows in parallel (group = row, lane-in-group = myv) ----
    const size_t row = r0 + grp;
    const float p = tanhf(myd + bv);
    float ss = p * p;
    ss += __shfl_xor(ss, 1, 64);
    ss += __shfl_xor(ss, 2, 64);
    ss += __shfl_xor(ss, 4, 64);
    const float av = p * (1.0f / fmaxf(sqrtf(ss), 1e-12f));

    // complex matvec: lane contributes column myv; halving-reduce the
    // 16-vector [cr0,ci0,cr1,ci1,...] over the 8-lane group
    float q[16];
#pragma unroll
    for (int i = 0; i < 8; ++i) {
      q[2 * i]     = Ur[i] * av;
      q[2 * i + 1] = Ui[i] * av;
    }
    float n8[8];
#pragma unroll
    for (int i = 0; i < 8; ++i) {
      const float k1 = b0 ? q[i + 8] : q[i];
      const float s1v = b0 ? q[i] : q[i + 8];
      n8[i] = k1 + __shfl_xor(s1v, 1, 64);
    }
    float n4[4];
#pragma unroll
    for (int i = 0; i < 4; ++i) {
      const float k2 = b1 ? n8[i + 4] : n8[i];
      const float s2v = b1 ? n8[i] : n8[i + 4];
      n4[i] = k2 + __shfl_xor(s2v, 2, 64);
    }
    float n2[2];
#pragma unroll
    for (int i = 0; i < 2; ++i) {
      const float k3 = b2 ? n4[i + 2] : n4[i];
      const float s3v = b2 ? n4[i] : n4[i + 2];
      n2[i] = k3 + __shfl_xor(s3v, 4, 64);
    }
    // lane holds cr,ci for state index i = myv
    const float pr = n2[0] * n2[0] + n2[1] * n2[1];
    // <Z_q>: sign by bit (4>>q) of state index
    float t0 = (myv & 4) ? -pr : pr;
    float t1 = (myv & 2) ? -pr : pr;
    float t2 = (myv & 1) ? -pr : pr;
#pragma unroll
    for (int m = 1; m <= 4; m <<= 1) {
      t0 += __shfl_xor(t0, m, 64);
      t1 += __shfl_xor(t1, m, 64);
      t2 += __shfl_xor(t2, m, 64);
    }
    if (!GUARD || row < (size_t)B) {
      float* o = out + row * 11;
      o[myv] = p;
      if (myv < 3) o[8 + myv] = (myv == 0) ? t0 : ((myv == 1) ? t1 : t2);
    }
  }
}

extern "C" void kernel_launch(void* const* d_in, const int* in_sizes, int n_in,
                              void* d_out, int out_size, void* d_ws, size_t ws_size,
                              hipStream_t stream) {
  const float* x  = (const float*)d_in[0];   // (B, 512)
  const float* W  = (const float*)d_in[1];   // (8, 512)
  const float* b  = (const float*)d_in[2];   // (8,)
  const float* wq = (const float*)d_in[3];   // (2, 2, 3)
  float* out = (float*)d_out;                // (B, 11)
  float* Uws = (float*)d_ws;                 // 128 floats

  const int B = in_sizes[0] / 512;

  vqc_build_u<<<1, 64, 0, stream>>>(wq, Uws);
  if (B & 7)
    vqc_fused<true><<<2048, 256, 0, stream>>>(x, W, b, Uws, out, B);
  else
    vqc_fused<false><<<2048, 256, 0, stream>>>(x, W, b, Uws, out, B);
}